// Round 1
// baseline (75.765 us; speedup 1.0000x reference)
//
#include <hip/hip_runtime.h>

#define HH 32
#define WW 32
#define NPOS 512
#define TILE 4            // spatial positions per block (4-wide row segment)
#define PPAD 516          // padded p-stride: 516 % 32 == 4 -> conflict-free float4 dot reads
#define NTHR 512
#define NBLK 256          // 32 rows x 8 col-segments -> one block per CU, full device
#define NLAYERS 4
#define FSTR 16           // ints per flag slot (64 B) -> one cache line per flag
#define FLAGV(L) (0x5EED0001 + (L))   // != 0xAAAAAAAA ws-poison -> no memset needed

// Device-coherent (cross-XCD) state access: relaxed agent-scope atomics.
__device__ __forceinline__ float ld_dev(const float* p) {
    return __hip_atomic_load(p, __ATOMIC_RELAXED, __HIP_MEMORY_SCOPE_AGENT);
}
__device__ __forceinline__ void st_dev(float* p, float v) {
    __hip_atomic_store(p, v, __ATOMIC_RELAXED, __HIP_MEMORY_SCOPE_AGENT);
}

// Neighbor-local sync: producer flag = sc1 STORE of a layer-unique magic.
// __syncthreads drains vmcnt before s_barrier -> sc1 state stores acked first.
__device__ __forceinline__ void neighbor_sync(int* flags, int layer, int h, int seg) {
    __syncthreads();                       // drain: state stores acked
    const int t = threadIdx.x;
    if (t == 0) {
        __hip_atomic_store(&flags[(layer * NBLK + (h * 8 + seg)) * FSTR], FLAGV(layer),
                           __ATOMIC_RELAXED, __HIP_MEMORY_SCOPE_AGENT);
    }
    if (t < 9) {                           // poll the 9 producer tiles
        int dr = t / 3, ds = t % 3 - 1;    // rows h..h+2, segs seg-1..seg+1
        int pid = (((h + dr) & 31) * 8) | ((seg + ds) & 7);
        const int* f = &flags[(layer * NBLK + pid) * FSTR];
        while (__hip_atomic_load(f, __ATOMIC_RELAXED, __HIP_MEMORY_SCOPE_AGENT) != FLAGV(layer)) {
            __builtin_amdgcn_s_sleep(2);
        }
    }
    __syncthreads();
}

__device__ __forceinline__ void make_v(const float c[9], float* v) {
    // v[lo] over window elems m=4..8 (MSB-first: c4 -> bit4, c8 -> bit0)
    float a2[2], a4[4], a8[8], a16[16];
    a2[0] = 1.0f - c[4]; a2[1] = c[4];
    #pragma unroll
    for (int i = 0; i < 2; ++i)  { a4[2*i]  = a2[i]  * (1.0f - c[5]); a4[2*i+1]  = a2[i]  * c[5]; }
    #pragma unroll
    for (int i = 0; i < 4; ++i)  { a8[2*i]  = a4[i]  * (1.0f - c[6]); a8[2*i+1]  = a4[i]  * c[6]; }
    #pragma unroll
    for (int i = 0; i < 8; ++i)  { a16[2*i] = a8[i]  * (1.0f - c[7]); a16[2*i+1] = a8[i]  * c[7]; }
    #pragma unroll
    for (int i = 0; i < 16; ++i) { v[2*i]   = a16[i] * (1.0f - c[8]); v[2*i+1]   = a16[i] * c[8]; }
}

__device__ __forceinline__ float sigm(float g) {
    return __builtin_amdgcn_rcpf(1.0f + __expf(-g));
}

__global__ __launch_bounds__(NTHR) void asic_fused(
    const float* __restrict__ x,     // (16,32,32)
    const float* __restrict__ tg,    // (4,512,32,32)
    float* __restrict__ bufA,        // layer-0 state
    float* __restrict__ bufB,        // layer-1 state
    float* __restrict__ bufC,        // layer-2 state (own buffer: WAR-safe under skew)
    float* __restrict__ out,         // layer-3 state
    int* __restrict__ flags)         // 3*256 flag slots (poisoned 0xAA, no memset)
{
    __shared__ float  lut[NLAYERS][TILE * PPAD];  // 33 KB: all layers
    __shared__ float2 red[16][33];                // 4.2 KB

    const int t   = threadIdx.x;          // 0..511
    const int bid = blockIdx.x;
    // XCD swizzle invariant: bid = h + 32*seg -> bid mod 8 == h mod 8 for all 8 segs
    // of a row -> same XCD L2 -> each tg row line fetched once, shared by 8 blocks.
    const int h   = bid & 31;             // tile row 0..31
    const int seg = bid >> 5;             // col segment 0..7
    const int w0  = seg * TILE;
    const int hw0 = h * 32 + w0;

    // ---- per-thread compute layout: pos(4) x batch-pair(8) x p-chunk(16)
    const int hwl = t & 3;                // position within 4-wide tile
    const int bp  = (t >> 2) & 7;         // batch pair -> batches 2bp, 2bp+1
    const int oct = t >> 5;               // 0..15: 32-p chunk, bits = (m0,m1,m2,m3)
    const int w   = w0 + hwl;
    const int b0  = 2 * bp;
    const int bit0 = (oct >> 3) & 1, bit1 = (oct >> 2) & 1;
    const int bit2 = (oct >> 1) & 1, bit3 = oct & 1;

    // ---- stage layer-0 LUT: one float4 per thread covers the whole 4-wide tile at p=t
    {
        float4 g4 = *(const float4*)(tg + t * (HH * WW) + hw0);
        lut[0][0 * PPAD + t] = sigm(g4.x);
        lut[0][1 * PPAD + t] = sigm(g4.y);
        lut[0][2 * PPAD + t] = sigm(g4.z);
        lut[0][3 * PPAD + t] = sigm(g4.w);
    }

    // ---- gather layer-0 windows from x (plain loads: input, coherent at dispatch)
    float c0[9], c1[9];
    {
        const float* s0 = x + b0 * (HH * WW);
        const float* s1 = s0 + (HH * WW);
        #pragma unroll
        for (int i = 0; i < 3; ++i) {
            int row = ((h + i) & 31) * 32;
            #pragma unroll
            for (int j = 0; j < 3; ++j) {
                int idx = row + ((w + j - 1 + 32) & 31);
                c0[3 * i + j] = s0[idx];
                c1[3 * i + j] = s1[idx];
            }
        }
    }

    __syncthreads();   // lut[0] ready

    // ---- stage layers 1..3 (one float4 per thread per layer): independent of
    //      layer-0 compute; compiler interleaves with the dot + first sync.
    #pragma unroll
    for (int layer = 1; layer < NLAYERS; ++layer) {
        float4 g4 = *(const float4*)(tg + (size_t)layer * NPOS * HH * WW + t * (HH * WW) + hw0);
        lut[layer][0 * PPAD + t] = sigm(g4.x);
        lut[layer][1 * PPAD + t] = sigm(g4.y);
        lut[layer][2 * PPAD + t] = sigm(g4.z);
        lut[layer][3 * PPAD + t] = sigm(g4.w);
    }

    float* dsts[NLAYERS] = {bufA, bufB, bufC, out};
    const float* src = x;

    for (int layer = 0; layer < NLAYERS; ++layer) {
        float* dst = dsts[layer];

        if (layer > 0) {   // gather via sc1 (cross-XCD coherent); layer 0 pre-gathered
            const float* s0 = src + b0 * (HH * WW);
            const float* s1 = s0 + (HH * WW);
            #pragma unroll
            for (int i = 0; i < 3; ++i) {
                int row = ((h + i) & 31) * 32;
                #pragma unroll
                for (int j = 0; j < 3; ++j) {
                    int idx = row + ((w + j - 1 + 32) & 31);
                    c0[3 * i + j] = ld_dev(s0 + idx);
                    c1[3 * i + j] = ld_dev(s1 + idx);
                }
            }
        }

        float v0[32], v1[32];
        make_v(c0, v0);
        make_v(c1, v1);

        // scalar weight for this thread's 32-p chunk: bits m0..m3 folded here
        float u0 = (bit0 ? c0[0] : 1.0f - c0[0]) * (bit1 ? c0[1] : 1.0f - c0[1])
                 * (bit2 ? c0[2] : 1.0f - c0[2]) * (bit3 ? c0[3] : 1.0f - c0[3]);
        float u1 = (bit0 ? c1[0] : 1.0f - c1[0]) * (bit1 ? c1[1] : 1.0f - c1[1])
                 * (bit2 ? c1[2] : 1.0f - c1[2]) * (bit3 ? c1[3] : 1.0f - c1[3]);

        // ---- dot: 8 b128 LDS reads, each FMA'd for both batches
        const float4* A = (const float4*)(&lut[layer][0] + hwl * PPAD) + oct * 8;
        float sA0 = 0.f, sA1 = 0.f;
        #pragma unroll
        for (int l4 = 0; l4 < 8; ++l4) {
            float4 LA = A[l4];
            sA0 = fmaf(LA.x, v0[4*l4+0], sA0); sA0 = fmaf(LA.y, v0[4*l4+1], sA0);
            sA0 = fmaf(LA.z, v0[4*l4+2], sA0); sA0 = fmaf(LA.w, v0[4*l4+3], sA0);
            sA1 = fmaf(LA.x, v1[4*l4+0], sA1); sA1 = fmaf(LA.y, v1[4*l4+1], sA1);
            sA1 = fmaf(LA.z, v1[4*l4+2], sA1); sA1 = fmaf(LA.w, v1[4*l4+3], sA1);
        }

        red[oct][t & 31] = make_float2(u0 * sA0, u1 * sA1);   // t&31 == bp*4 + hwl
        __syncthreads();

        if (t < 64) {
            int pos = t & 3;
            int bpi = (t >> 2) & 7;
            int par = t >> 5;                 // 0 -> batch 2bpi, 1 -> 2bpi+1
            float s = 0.0f;
            #pragma unroll
            for (int g = 0; g < 16; ++g) {
                float2 r = red[g][bpi * 4 + pos];
                s += par ? r.y : r.x;
            }
            s = fminf(fmaxf(s, 0.0f), 1.0f);
            st_dev(dst + (size_t)(2 * bpi + par) * (HH * WW) + h * 32 + w0 + pos, s);
        }

        if (layer < NLAYERS - 1) neighbor_sync(flags, layer, h, seg);
        src = dst;
    }
}

extern "C" void kernel_launch(void* const* d_in, const int* in_sizes, int n_in,
                              void* d_out, int out_size, void* d_ws, size_t ws_size,
                              hipStream_t stream) {
    const float* x  = (const float*)d_in[0];   // (16,32,32)
    const float* tg = (const float*)d_in[1];   // (4,512,32,32)
    float* out  = (float*)d_out;
    float* bufA = (float*)d_ws;                          // 64 KB
    float* bufB = bufA + 16 * HH * WW;                   // 64 KB
    float* bufC = bufB + 16 * HH * WW;                   // 64 KB
    int*   flags = (int*)((char*)d_ws + 256 * 1024);     // 3*256 slots x 64 B

    // no memset: flags are poison-valued 0xAAAAAAAA; producers store FLAGV(layer)
    asic_fused<<<NBLK, NTHR, 0, stream>>>(x, tg, bufA, bufB, bufC, out, flags);
}

// Round 2
// 69.970 us; speedup vs baseline: 1.0828x; 1.0828x over previous
//
#include <hip/hip_runtime.h>

#define HH 32
#define WW 32
#define NPOS 512
#define TILE 8            // spatial positions per block (row segment)
#define PPAD 516          // padded p-stride: 516 % 32 == 4 -> conflict-free float4 dot reads
#define NTHR 512          // two 256-thread batch-half groups sharing one LUT
#define NBLK 128          // 32 rows x 4 col-segments; co-residency proven
#define NLAYERS 4
#define RPAD 33           // float2 stride per oct in reduction buffer
#define FSTR 16           // ints per flag slot (64 B) -> one cache line per flag
#define FLAGV(L) (0x5EED0001 + (L))   // != 0xAAAAAAAA ws-poison -> no memset needed
#define NHALO (16 * 3 * 10)           // batches x rows x cols = 480 unique halo floats

// Device-coherent (cross-XCD) state access: relaxed agent-scope atomics (sc1,
// serviced at the shared coherence point; no L1/L2 staleness possible).
__device__ __forceinline__ float ld_dev(const float* p) {
    return __hip_atomic_load(p, __ATOMIC_RELAXED, __HIP_MEMORY_SCOPE_AGENT);
}
__device__ __forceinline__ void st_dev(float* p, float v) {
    __hip_atomic_store(p, v, __ATOMIC_RELAXED, __HIP_MEMORY_SCOPE_AGENT);
}

// Neighbor-local sync (validated): producer flag = sc1 STORE of a layer-unique
// magic (poison can't match -> no memset). __syncthreads drains vmcnt before
// s_barrier, so sc1 state stores are acked before publishing.
__device__ __forceinline__ void neighbor_sync(int* flags, int layer, int h, int seg) {
    __syncthreads();                       // drain: state stores acked
    const int t = threadIdx.x;
    if (t == 0) {
        __hip_atomic_store(&flags[(layer * NBLK + (h * 4 + seg)) * FSTR], FLAGV(layer),
                           __ATOMIC_RELAXED, __HIP_MEMORY_SCOPE_AGENT);
    }
    if (t < 9) {                           // poll the 9 producer tiles
        int dr = t / 3, ds = t % 3 - 1;    // rows h..h+2, segs seg-1..seg+1
        int pid = (((h + dr) & 31) << 2) | ((seg + ds) & 3);
        const int* f = &flags[(layer * NBLK + pid) * FSTR];
        while (__hip_atomic_load(f, __ATOMIC_RELAXED, __HIP_MEMORY_SCOPE_AGENT) != FLAGV(layer)) {
            __builtin_amdgcn_s_sleep(2);
        }
    }
    __syncthreads();
}

__device__ __forceinline__ void make_v(const float c[9], float* v) {
    // v[lo] over window elems m=4..8 (MSB-first)
    float a2[2], a4[4], a8[8], a16[16];
    a2[0] = 1.0f - c[4]; a2[1] = c[4];
    #pragma unroll
    for (int i = 0; i < 2; ++i)  { a4[2*i]  = a2[i]  * (1.0f - c[5]); a4[2*i+1]  = a2[i]  * c[5]; }
    #pragma unroll
    for (int i = 0; i < 4; ++i)  { a8[2*i]  = a4[i]  * (1.0f - c[6]); a8[2*i+1]  = a4[i]  * c[6]; }
    #pragma unroll
    for (int i = 0; i < 8; ++i)  { a16[2*i] = a8[i]  * (1.0f - c[7]); a16[2*i+1] = a8[i]  * c[7]; }
    #pragma unroll
    for (int i = 0; i < 16; ++i) { v[2*i]   = a16[i] * (1.0f - c[8]); v[2*i+1]   = a16[i] * c[8]; }
}

__device__ __forceinline__ float sigm(float g) {
    return __builtin_amdgcn_rcpf(1.0f + __expf(-g));
}

__global__ __launch_bounds__(NTHR) void asic_fused(
    const float* __restrict__ x,     // (16,32,32)
    const float* __restrict__ tg,    // (4,512,32,32)
    float* __restrict__ bufA,        // layer-0 state
    float* __restrict__ bufB,        // layer-1 state
    float* __restrict__ bufC,        // layer-2 state (own buffer: WAR-safe under skew)
    float* __restrict__ out,         // layer-3 state
    int* __restrict__ flags)         // 3*128 flag slots (poisoned 0xAA, no memset)
{
    __shared__ float  lut[NLAYERS][TILE * PPAD];  // 66 KB: all layers
    __shared__ float2 red[2][8 * RPAD];           // 4.2 KB
    __shared__ float  halo[NHALO];                // 1.9 KB: staged inter-layer gather

    const int t   = threadIdx.x;          // 0..511
    const int bid = blockIdx.x;
    // XCD swizzle: segs of one row -> bids {r, r+32, r+64, r+96}, all == r mod 8
    // -> same XCD L2 -> the shared 128-B gate lines are fetched once, not 4x.
    const int h   = bid & 31;             // tile row 0..31
    const int seg = bid >> 5;             // col segment 0..3
    const int w0  = seg * TILE;
    const int hw0 = h * 32 + w0;

    // ---- per-half compute layout
    const int th    = t & 255;
    const int bhalf = t >> 8;
    const int hwl   = th & 7;
    const int bp    = (th >> 3) & 3;
    const int oct   = th >> 5;            // hi = 2*oct, 2*oct+1
    const int w     = w0 + hwl;
    const int b0    = bhalf * 8 + 2 * bp;
    const int bit0 = (oct >> 2) & 1, bit1 = (oct >> 1) & 1, bit2 = oct & 1;

    // ---- halo-stage decomposition for t < 480: one unique ld_dev per thread
    const int hb = t / 30;                // batch 0..15
    const int hr = t - hb * 30;
    const int hi = hr / 10;               // window row 0..2
    const int hj = hr - hi * 10;          // halo col 0..9  (grid col = w0-1+hj)
    const int hoff = hb * (HH * WW) + (((h + hi) & 31) << 5) + ((w0 - 1 + hj + 32) & 31);

    // ---- stage layer-0 LUT (float4 loads: 2 iters, 4x bytes in flight)
    #pragma unroll
    for (int k = 0; k < 2; ++k) {
        int f    = t + NTHR * k;          // 0..1023
        int p    = f >> 1;
        int half = f & 1;                 // positions 4*half .. 4*half+3
        float4 g4 = *(const float4*)(tg + p * (HH * WW) + hw0 + half * 4);
        int pb = half * 4;
        lut[0][(pb + 0) * PPAD + p] = sigm(g4.x);
        lut[0][(pb + 1) * PPAD + p] = sigm(g4.y);
        lut[0][(pb + 2) * PPAD + p] = sigm(g4.z);
        lut[0][(pb + 3) * PPAD + p] = sigm(g4.w);
    }

    // ---- gather layer-0 windows from x (plain loads: input, coherent at dispatch)
    float c0[9], c1[9];
    {
        const float* s0 = x + b0 * (HH * WW);
        const float* s1 = s0 + (HH * WW);
        #pragma unroll
        for (int i = 0; i < 3; ++i) {
            int row = ((h + i) & 31) * 32;
            #pragma unroll
            for (int j = 0; j < 3; ++j) {
                int idx = row + ((w + j - 1 + 32) & 31);
                c0[3 * i + j] = s0[idx];
                c1[3 * i + j] = s1[idx];
            }
        }
    }

    __syncthreads();   // lut[0] ready

    // ---- stage layers 1..3 (6 float4 iters): independent of layer-0 compute;
    //      compiler interleaves these loads/sigmoids with the dot + first sync.
    #pragma unroll
    for (int k = 0; k < 6; ++k) {
        int f     = t + NTHR * k;         // 0..3071
        int layer = 1 + (f >> 10);
        int r     = f & 1023;
        int p     = r >> 1;
        int half  = r & 1;
        float4 g4 = *(const float4*)(tg + (size_t)layer * NPOS * HH * WW + p * (HH * WW) + hw0 + half * 4);
        int pb = half * 4;
        lut[layer][(pb + 0) * PPAD + p] = sigm(g4.x);
        lut[layer][(pb + 1) * PPAD + p] = sigm(g4.y);
        lut[layer][(pb + 2) * PPAD + p] = sigm(g4.z);
        lut[layer][(pb + 3) * PPAD + p] = sigm(g4.w);
    }

    float* dsts[NLAYERS] = {bufA, bufB, bufC, out};
    const float* src = x;

    for (int layer = 0; layer < NLAYERS; ++layer) {
        float* dst = dsts[layer];

        if (layer > 0) {
            // ---- staged gather: 480 unique sc1 loads (12x fewer LLC transactions
            //      than per-thread gather), then window reads from LDS (<=2-way).
            if (t < NHALO) halo[t] = ld_dev(src + hoff);
            __syncthreads();               // halo ready
            const float* h0 = halo + b0 * 30;
            const float* h1 = h0 + 30;
            #pragma unroll
            for (int i = 0; i < 3; ++i) {
                #pragma unroll
                for (int j = 0; j < 3; ++j) {
                    c0[3 * i + j] = h0[i * 10 + hwl + j];
                    c1[3 * i + j] = h1[i * 10 + hwl + j];
                }
            }
        }

        float v0[32], v1[32];
        make_v(c0, v0);
        make_v(c1, v1);

        float base0 = (bit0 ? c0[0] : 1.0f - c0[0]) * (bit1 ? c0[1] : 1.0f - c0[1]) * (bit2 ? c0[2] : 1.0f - c0[2]);
        float base1 = (bit0 ? c1[0] : 1.0f - c1[0]) * (bit1 ? c1[1] : 1.0f - c1[1]) * (bit2 ? c1[2] : 1.0f - c1[2]);
        float uA0 = base0 * (1.0f - c0[3]), uB0 = base0 * c0[3];
        float uA1 = base1 * (1.0f - c1[3]), uB1 = base1 * c1[3];

        // ---- dot: 16 b128 LDS reads, each FMA'd for both batches
        const float4* lutp = (const float4*)(&lut[layer][0] + hwl * PPAD);
        const float4* A = lutp + (2 * oct) * 8;
        const float4* B = A + 8;
        float sA0 = 0.f, sA1 = 0.f, sB0 = 0.f, sB1 = 0.f;
        #pragma unroll
        for (int l4 = 0; l4 < 8; ++l4) {
            float4 LA = A[l4];
            float4 LB = B[l4];
            sA0 = fmaf(LA.x, v0[4*l4+0], sA0); sA0 = fmaf(LA.y, v0[4*l4+1], sA0);
            sA0 = fmaf(LA.z, v0[4*l4+2], sA0); sA0 = fmaf(LA.w, v0[4*l4+3], sA0);
            sA1 = fmaf(LA.x, v1[4*l4+0], sA1); sA1 = fmaf(LA.y, v1[4*l4+1], sA1);
            sA1 = fmaf(LA.z, v1[4*l4+2], sA1); sA1 = fmaf(LA.w, v1[4*l4+3], sA1);
            sB0 = fmaf(LB.x, v0[4*l4+0], sB0); sB0 = fmaf(LB.y, v0[4*l4+1], sB0);
            sB0 = fmaf(LB.z, v0[4*l4+2], sB0); sB0 = fmaf(LB.w, v0[4*l4+3], sB0);
            sB1 = fmaf(LB.x, v1[4*l4+0], sB1); sB1 = fmaf(LB.y, v1[4*l4+1], sB1);
            sB1 = fmaf(LB.z, v1[4*l4+2], sB1); sB1 = fmaf(LB.w, v1[4*l4+3], sB1);
        }
        float acc0 = fmaf(uA0, sA0, uB0 * sB0);
        float acc1 = fmaf(uA1, sA1, uB1 * sB1);

        red[bhalf][oct * RPAD + bp * 8 + hwl] = make_float2(acc0, acc1);
        __syncthreads();

        if (th < 64) {
            int hw  = th & 7;
            int bl  = th >> 3;
            int bpi = bl >> 1, par = bl & 1;
            float s = 0.0f;
            #pragma unroll
            for (int o = 0; o < 8; ++o) {
                float2 r = red[bhalf][o * RPAD + bpi * 8 + hw];
                s += par ? r.y : r.x;
            }
            s = fminf(fmaxf(s, 0.0f), 1.0f);
            st_dev(dst + (size_t)(bhalf * 8 + bl) * (HH * WW) + h * 32 + w0 + hw, s);
        }

        if (layer < NLAYERS - 1) neighbor_sync(flags, layer, h, seg);
        src = dst;
    }
}

extern "C" void kernel_launch(void* const* d_in, const int* in_sizes, int n_in,
                              void* d_out, int out_size, void* d_ws, size_t ws_size,
                              hipStream_t stream) {
    const float* x  = (const float*)d_in[0];   // (16,32,32)
    const float* tg = (const float*)d_in[1];   // (4,512,32,32)
    float* out  = (float*)d_out;
    float* bufA = (float*)d_ws;                          // 64 KB
    float* bufB = bufA + 16 * HH * WW;                   // 64 KB
    float* bufC = bufB + 16 * HH * WW;                   // 64 KB
    int*   flags = (int*)((char*)d_ws + 256 * 1024);     // 3*128 slots x 64 B

    // no memset: flags are poison-valued 0xAAAAAAAA; producers store FLAGV(layer)
    asic_fused<<<NBLK, NTHR, 0, stream>>>(x, tg, bufA, bufB, bufC, out, flags);
}